// Round 10
// baseline (202.315 us; speedup 1.0000x reference)
//
#include <hip/hip_runtime.h>

#define D_MODEL 1024
#define NHEAD 16
#define HD 64
#define BATCH 2
#define SEQ 2048

typedef unsigned short u16;
typedef unsigned int u32;
typedef __bf16 bf16x8 __attribute__((ext_vector_type(8)));
typedef unsigned short u16x8 __attribute__((ext_vector_type(8)));
typedef short s16x4 __attribute__((ext_vector_type(4)));
typedef float f32x4 __attribute__((ext_vector_type(4)));

#if defined(__has_builtin)
#if __has_builtin(__builtin_amdgcn_exp2f)
#define EXP2(x) __builtin_amdgcn_exp2f(x)
#else
#define EXP2(x) exp2f(x)
#endif
#else
#define EXP2(x) exp2f(x)
#endif

// fp32 -> bf16 round-to-nearest-even
static __device__ __forceinline__ u16 f2bf(float f) {
    union { float f; unsigned u; } v; v.f = f;
    unsigned u = v.u;
    u += 0x7fffu + ((u >> 16) & 1u);
    return (u16)(u >> 16);
}

static __device__ __forceinline__ void gld_lds16(const void* g, void* l) {
    __builtin_amdgcn_global_load_lds(
        (const __attribute__((address_space(1))) void*)g,
        (__attribute__((address_space(3))) void*)l, 16, 0, 0);
}

// pack 8 fp32 -> 8 bf16 (truncation) via v_perm_b32
static __device__ __forceinline__ bf16x8 pack_bf8(f32x4 a, f32x4 b) {
    union { float f; unsigned u; } a0, a1, a2, a3, b0, b1, b2, b3;
    a0.f = a[0]; a1.f = a[1]; a2.f = a[2]; a3.f = a[3];
    b0.f = b[0]; b1.f = b[1]; b2.f = b[2]; b3.f = b[3];
    union { unsigned u[4]; bf16x8 v; } r;
    r.u[0] = __builtin_amdgcn_perm(a1.u, a0.u, 0x07060302u);
    r.u[1] = __builtin_amdgcn_perm(a3.u, a2.u, 0x07060302u);
    r.u[2] = __builtin_amdgcn_perm(b1.u, b0.u, 0x07060302u);
    r.u[3] = __builtin_amdgcn_perm(b3.u, b2.u, 0x07060302u);
    return r.v;
}

// ---------------- pass 0: x fp32->bf16 (z==0) and W fp32->bf16 transposed (z=1..4) ----------------
__global__ __launch_bounds__(256) void k_convert(const float* __restrict__ x,
                                                 const float* __restrict__ wq,
                                                 const float* __restrict__ wk,
                                                 const float* __restrict__ wv,
                                                 const float* __restrict__ wo,
                                                 u16* __restrict__ xb,
                                                 u16* __restrict__ wt) {
    int z = blockIdx.z;
    if (z == 0) {
        int base = (blockIdx.y * 32 + blockIdx.x) * 256 + threadIdx.x;
#pragma unroll
        for (int p = 0; p < 4; p++) {
            int i = base + p * 262144;
            float4 v = ((const float4*)x)[i];
            ushort4 o = make_ushort4(f2bf(v.x), f2bf(v.y), f2bf(v.z), f2bf(v.w));
            ((ushort4*)xb)[i] = o;
        }
        return;
    }
    __shared__ u16 t[32][33];
    const float* W = z == 1 ? wq : z == 2 ? wk : z == 3 ? wv : wo;
    u16* dst = wt + (size_t)(z - 1) * (D_MODEL * D_MODEL);
    int tx = threadIdx.x & 31, ty = threadIdx.x >> 5;
    int n0 = blockIdx.x * 32, k0 = blockIdx.y * 32;
#pragma unroll
    for (int i = 0; i < 4; i++)
        t[ty + i * 8][tx] = f2bf(W[(size_t)(k0 + ty + i * 8) * D_MODEL + n0 + tx]);
    __syncthreads();
#pragma unroll
    for (int i = 0; i < 4; i++)
        dst[(size_t)(n0 + ty + i * 8) * D_MODEL + k0 + tx] = t[tx][ty + i * 8];
}

// ---------------- QKV GEMM: 128x128 tile, BK=32, double-buffered LDS, T1 swizzle ----------------
// V^T output (z==2) is written with key-quad interleave within each 32-key
// group: k = h*16 + q*4 + i  ->  p = q*8 + h*4 + i. This makes k_attn's PV
// B-frag (keys {lq*4+i} u {16+lq*4+i}) one contiguous b128 at col lq*8.
__global__ __launch_bounds__(256) void k_gemm(const u16* __restrict__ A,
                                              const u16* __restrict__ WtBase,
                                              const float* __restrict__ b0,
                                              const float* __restrict__ b1,
                                              const float* __restrict__ b2,
                                              u16* __restrict__ oq, u16* __restrict__ ok,
                                              u16* __restrict__ ov) {
    __shared__ u16 lA[2 * 128 * 32];   // [buf][row][32]
    __shared__ u16 lB[2 * 128 * 32];
    int tid = threadIdx.x, w = tid >> 6, l = tid & 63, lr = l & 15, lq = l >> 4;
    int z = blockIdx.z;
    const u16* Wt = WtBase + (size_t)z * (D_MODEL * D_MODEL);
    const float* bias = z == 0 ? b0 : z == 1 ? b1 : b2;
    float scale = (z == 0) ? (0.125f * 1.44269504088896340736f) : 1.0f;
    // per-z XCD swizzle: 256 blocks, 256%8==0, q=32
    int fid2 = blockIdx.y * 8 + blockIdx.x;
    int swz = (fid2 & 7) * 32 + (fid2 >> 3);
    int bx = swz & 7, by = swz >> 3;
    int m0 = by * 128, n0 = bx * 128;
    int wm = (w >> 1) * 64, wn = (w & 1) * 64;
    f32x4 acc[4][4];
#pragma unroll
    for (int mi = 0; mi < 4; mi++)
#pragma unroll
        for (int ni = 0; ni < 4; ni++) acc[mi][ni] = (f32x4){0.f, 0.f, 0.f, 0.f};

    int ra = tid >> 2, ca = (tid & 3) * 8;
    const u16* Aba = A + (size_t)(m0 + ra) * D_MODEL + ca;
    const u16* Abb = A + (size_t)(m0 + 64 + ra) * D_MODEL + ca;
    const u16* Bba = Wt + (size_t)(n0 + ra) * D_MODEL + ca;
    const u16* Bbb = Wt + (size_t)(n0 + 64 + ra) * D_MODEL + ca;

    auto stage = [&](int kk, int buf) {
        gld_lds16(Aba + kk, &lA[buf * 4096 + w * 512]);
        gld_lds16(Abb + kk, &lA[buf * 4096 + 2048 + w * 512]);
        gld_lds16(Bba + kk, &lB[buf * 4096 + w * 512]);
        gld_lds16(Bbb + kk, &lB[buf * 4096 + 2048 + w * 512]);
    };

    stage(0, 0);
    __syncthreads();
    int cur = 0;
    for (int t = 0; t < 32; ++t) {
        if (t + 1 < 32) stage((t + 1) * 32, cur ^ 1);
        bf16x8 af[4], bf[4];
#pragma unroll
        for (int mi = 0; mi < 4; mi++)
            af[mi] = *(const bf16x8*)&lA[cur * 4096 + (wm + mi * 16 + lr) * 32 + lq * 8];
#pragma unroll
        for (int ni = 0; ni < 4; ni++)
            bf[ni] = *(const bf16x8*)&lB[cur * 4096 + (wn + ni * 16 + lr) * 32 + lq * 8];
        __builtin_amdgcn_s_setprio(1);
#pragma unroll
        for (int mi = 0; mi < 4; mi++)
#pragma unroll
            for (int ni = 0; ni < 4; ni++)
                acc[mi][ni] = __builtin_amdgcn_mfma_f32_16x16x32_bf16(
                    af[mi], bf[ni], acc[mi][ni], 0, 0, 0);
        __builtin_amdgcn_s_setprio(0);
        __syncthreads();   // vmcnt(0)+lgkmcnt(0)+barrier: publishes buf cur^1
        cur ^= 1;
    }
#pragma unroll
    for (int mi = 0; mi < 4; mi++) {
#pragma unroll
        for (int ni = 0; ni < 4; ni++) {
            int col = n0 + wn + ni * 16 + lr;
            float bval = bias[col];
            int row0 = m0 + wm + mi * 16 + lq * 4;
            if (z == 2) {
                int b = row0 >> 11, s = row0 & 2047;
                int h = col >> 6, dd = col & 63;
                // key-quad interleave: p = (s&~31) | q*8 | h*4  (s%4==0 here)
                int sp = (s & ~31) | ((s & 12) << 1) | ((s & 16) >> 2);
                ushort4 pk;
                pk.x = f2bf(acc[mi][ni][0] + bval);
                pk.y = f2bf(acc[mi][ni][1] + bval);
                pk.z = f2bf(acc[mi][ni][2] + bval);
                pk.w = f2bf(acc[mi][ni][3] + bval);
                *(ushort4*)&ov[((size_t)(b * NHEAD + h) * HD + dd) * SEQ + sp] = pk;
            } else {
#pragma unroll
                for (int r = 0; r < 4; r++) {
                    int row = row0 + r;
                    float val = (acc[mi][ni][r] + bval) * scale;
                    u16* op = z == 0 ? oq : ok;
                    int b = row >> 11, s = row & 2047, h = col >> 6, d = col & 63;
                    op[(((size_t)(b * NHEAD + h)) * SEQ + s) * HD + d] = f2bf(val);
                }
            }
        }
    }
}

// ---------------- output GEMM + fused combine: 64x64 tiles, BK=32, dbuf LDS, T1 swizzle ----------------
// When P1 != null (key-split path), A-staging is reg-staged (T14): load both
// fp16 partials early (hides HBM latency under MFMA), after compute apply
// (p0+p1)*inv with RTNE f2bf (bit-identical to old k_combine) and ds_write
// into the next buffer. buf^1 was last read in iter t-1 (ended by barrier),
// so writing it during iter t is race-free. Eliminates the k_combine kernel
// and 16 MB of HBM traffic. B stays global_load_lds.
__global__ __launch_bounds__(256) void k_gout(const u16* __restrict__ P0,
                                              const u16* __restrict__ P1,
                                              const float* __restrict__ lsum,
                                              const u16* __restrict__ Wt,
                                              const float* __restrict__ bias,
                                              float* __restrict__ outf) {
    __shared__ u16 lA[2 * 64 * 32];
    __shared__ u16 lB[2 * 64 * 32];
    int tid = threadIdx.x, w = tid >> 6, l = tid & 63, lr = l & 15, lq = l >> 4;
    // 1024 blocks, q=128
    int fid = blockIdx.y * 16 + blockIdx.x;
    int swz = (fid & 7) * 128 + (fid >> 3);
    int bx = swz & 15, by = swz >> 4;
    int m0 = by * 64, n0 = bx * 64;
    int wm = (w >> 1) * 32, wn = (w & 1) * 32;
    f32x4 acc[2][2];
#pragma unroll
    for (int mi = 0; mi < 2; mi++)
#pragma unroll
        for (int ni = 0; ni < 2; ni++) acc[mi][ni] = (f32x4){0.f, 0.f, 0.f, 0.f};

    int ra = tid >> 2, ca = (tid & 3) * 8;
    int row = m0 + ra;
    int rb = row >> 11, rq = row & 2047;
    const u16* Pa = P0 + (size_t)row * D_MODEL + ca;
    const u16* Pb = P1 ? (P1 + (size_t)row * D_MODEL + ca) : P0;
    const u16* Bba = Wt + (size_t)(n0 + ra) * D_MODEL + ca;
    bool fused = (P1 != nullptr);

    u16x8 r0, r1;
    auto ldA = [&](int kk) {   // issue global loads of both partials (fp16)
        r0 = *(const u16x8*)(Pa + kk);
        r1 = *(const u16x8*)(Pb + kk);
    };
    auto wrA = [&](int kk, int buf) {   // combine + RTNE bf16 + ds_write_b128
        int h = kk >> 6;
        int mi2 = ((rb << 4) + h) * 2048 + rq;
        float inv = 1.0f / (lsum[mi2] + lsum[65536 + mi2]);
        u16x8 outv;
#pragma unroll
        for (int j = 0; j < 8; j++) {
            union { _Float16 hh; u16 uu; } c0, c1;
            c0.uu = r0[j]; c1.uu = r1[j];
            outv[j] = f2bf(((float)c0.hh + (float)c1.hh) * inv);
        }
        *(u16x8*)&lA[buf * 2048 + ra * 32 + ca] = outv;
    };

    if (fused) {
        ldA(0);
        wrA(0, 0);
    } else {
        gld_lds16(Pa, &lA[w * 512]);
    }
    gld_lds16(Bba, &lB[w * 512]);
    __syncthreads();
    int cur = 0;
    for (int t = 0; t < 32; ++t) {
        if (t + 1 < 32) {
            if (fused) ldA((t + 1) * 32);
            else gld_lds16(Pa + (t + 1) * 32, &lA[(cur ^ 1) * 2048 + w * 512]);
            gld_lds16(Bba + (t + 1) * 32, &lB[(cur ^ 1) * 2048 + w * 512]);
        }
        bf16x8 af[2], bf[2];
#pragma unroll
        for (int mi = 0; mi < 2; mi++)
            af[mi] = *(const bf16x8*)&lA[cur * 2048 + (wm + mi * 16 + lr) * 32 + lq * 8];
#pragma unroll
        for (int ni = 0; ni < 2; ni++)
            bf[ni] = *(const bf16x8*)&lB[cur * 2048 + (wn + ni * 16 + lr) * 32 + lq * 8];
        __builtin_amdgcn_s_setprio(1);
#pragma unroll
        for (int mi = 0; mi < 2; mi++)
#pragma unroll
            for (int ni = 0; ni < 2; ni++)
                acc[mi][ni] = __builtin_amdgcn_mfma_f32_16x16x32_bf16(
                    af[mi], bf[ni], acc[mi][ni], 0, 0, 0);
        __builtin_amdgcn_s_setprio(0);
        if (fused && t + 1 < 32) wrA((t + 1) * 32, cur ^ 1);
        __syncthreads();
        cur ^= 1;
    }
#pragma unroll
    for (int mi = 0; mi < 2; mi++)
#pragma unroll
        for (int ni = 0; ni < 2; ni++) {
            int col = n0 + wn + ni * 16 + lr;
            float bval = bias[col];
#pragma unroll
            for (int r = 0; r < 4; r++) {
                int orow = m0 + wm + mi * 16 + lq * 4 + r;
                outf[(size_t)orow * D_MODEL + col] = acc[mi][ni][r] + bval;
            }
        }
}

// ---------------- flash attention v11 (R8-proven best: setprio + b128 V-frag) ----------------
static __device__ __forceinline__ int ksw(int row, int col) {  // u16 idx into lK[128][64]
    return row * 64 + ((((col >> 3) ^ (row & 7)) << 3) | (col & 7));
}
static __device__ __forceinline__ int vsw(int row, int col) {  // u16 idx into lVt[64][128]
    return row * 128 + ((((col >> 3) ^ (row & 15)) << 3) | (col & 7));
}

__global__ __launch_bounds__(256) void k_attn(const u16* __restrict__ Q,
                                              const u16* __restrict__ K,
                                              const u16* __restrict__ VT,
                                              u16* __restrict__ part0,
                                              u16* __restrict__ part1,
                                              float* __restrict__ lsum, int nsplit) {
    __shared__ __align__(16) u16 lK[128 * 64];    // XOR-swizzled, see ksw()
    __shared__ __align__(16) u16 lVt[64 * 128];   // XOR-swizzled, see vsw()
    int tid = threadIdx.x, w = tid >> 6, l = tid & 63, lr = l & 15, lq = l >> 4;
    int bl = blockIdx.x;
    int qt = bl / (32 * nsplit);
    int rem = bl - qt * (32 * nsplit);
    int bh = rem / nsplit;
    int ks = rem - bh * nsplit;
    int qb = qt * 128 + w * 32;
    const u16* Qb = Q + (size_t)bh * SEQ * HD;
    const u16* Kb = K + (size_t)bh * SEQ * HD;
    const u16* VTb = VT + (size_t)bh * HD * SEQ;

    bf16x8 qf[2][2];
#pragma unroll
    for (int tq = 0; tq < 2; tq++)
#pragma unroll
        for (int kc = 0; kc < 2; kc++)
            qf[tq][kc] = *(const bf16x8*)&Qb[(size_t)(qb + tq * 16 + lr) * HD +
                                             kc * 32 + lq * 8];
    f32x4 o[2][4];
    f32x4 ol[2];    // l accumulator via ones-MFMA, same C-layout as o
#pragma unroll
    for (int tq = 0; tq < 2; tq++) {
        ol[tq] = (f32x4){0.f, 0.f, 0.f, 0.f};
#pragma unroll
        for (int di = 0; di < 4; di++) o[tq][di] = (f32x4){0.f, 0.f, 0.f, 0.f};
    }
    union { u16 s[8]; bf16x8 v; } onev;
#pragma unroll
    for (int i = 0; i < 8; i++) onev.s[i] = 0x3F80;
    const bf16x8 vone8 = onev.v;

    int krow = tid >> 3, kch = tid & 7;
    int vrow = tid >> 4, vch = tid & 15;

    int nk = SEQ / nsplit;
    int jbeg = ks * nk, jend = jbeg + nk;

    u16x8 kreg[4], vreg[4];
#pragma unroll
    for (int p = 0; p < 4; p++) {
        kreg[p] = *(const u16x8*)&Kb[(size_t)(jbeg + p * 32 + krow) * HD + kch * 8];
        vreg[p] = *(const u16x8*)&VTb[(size_t)(p * 16 + vrow) * SEQ + jbeg + vch * 8];
    }

    for (int j0 = jbeg; j0 < jend; j0 += 128) {
        __syncthreads();
#pragma unroll
        for (int p = 0; p < 4; p++) {
            *(u16x8*)&lK[ksw(p * 32 + krow, kch * 8)] = kreg[p];
            *(u16x8*)&lVt[vsw(p * 16 + vrow, vch * 8)] = vreg[p];
        }
        __syncthreads();
        if (j0 + 128 < jend) {
            int jn = j0 + 128;
#pragma unroll
            for (int p = 0; p < 4; p++) {
                kreg[p] = *(const u16x8*)&Kb[(size_t)(jn + p * 32 + krow) * HD + kch * 8];
                vreg[p] = *(const u16x8*)&VTb[(size_t)(p * 16 + vrow) * SEQ + jn + vch * 8];
            }
        }

#pragma unroll
        for (int kh = 0; kh < 2; kh++) {
#pragma unroll
            for (int t2 = 0; t2 < 2; t2++) {
                int rA = kh * 64 + t2 * 32 + lr;   // key tile A (keys +0..15)
                int rB = rA + 16;                  // key tile B (keys +16..31)
                bf16x8 kA0 = *(const bf16x8*)&lK[ksw(rA, lq * 8)];
                bf16x8 kA1 = *(const bf16x8*)&lK[ksw(rA, 32 + lq * 8)];
                bf16x8 kB0 = *(const bf16x8*)&lK[ksw(rB, lq * 8)];
                bf16x8 kB1 = *(const bf16x8*)&lK[ksw(rB, 32 + lq * 8)];
                f32x4 sA0 = (f32x4){0.f, 0.f, 0.f, 0.f};
                f32x4 sA1 = (f32x4){0.f, 0.f, 0.f, 0.f};
                f32x4 sB0 = (f32x4){0.f, 0.f, 0.f, 0.f};
                f32x4 sB1 = (f32x4){0.f, 0.f, 0.f, 0.f};
                __builtin_amdgcn_s_setprio(1);
                sA0 = __builtin_amdgcn_mfma_f32_16x16x32_bf16(kA0, qf[0][0], sA0, 0, 0, 0);
                sB0 = __builtin_amdgcn_mfma_f32_16x16x32_bf16(kB0, qf[0][0], sB0, 0, 0, 0);
                sA1 = __builtin_amdgcn_mfma_f32_16x16x32_bf16(kA0, qf[1][0], sA1, 0, 0, 0);
                sB1 = __builtin_amdgcn_mfma_f32_16x16x32_bf16(kB0, qf[1][0], sB1, 0, 0, 0);
                sA0 = __builtin_amdgcn_mfma_f32_16x16x32_bf16(kA1, qf[0][1], sA0, 0, 0, 0);
                sB0 = __builtin_amdgcn_mfma_f32_16x16x32_bf16(kB1, qf[0][1], sB0, 0, 0, 0);
                sA1 = __builtin_amdgcn_mfma_f32_16x16x32_bf16(kA1, qf[1][1], sA1, 0, 0, 0);
                sB1 = __builtin_amdgcn_mfma_f32_16x16x32_bf16(kB1, qf[1][1], sB1, 0, 0, 0);
                __builtin_amdgcn_s_setprio(0);
#pragma unroll
                for (int r = 0; r < 4; r++) {
                    sA0[r] = EXP2(sA0[r]);
                    sA1[r] = EXP2(sA1[r]);
                    sB0[r] = EXP2(sB0[r]);
                    sB1[r] = EXP2(sB1[r]);
                }
                bf16x8 pf0 = pack_bf8(sA0, sB0);
                bf16x8 pf1 = pack_bf8(sA1, sB1);
                __builtin_amdgcn_s_setprio(1);
                ol[0] = __builtin_amdgcn_mfma_f32_16x16x32_bf16(pf0, vone8, ol[0], 0, 0, 0);
                ol[1] = __builtin_amdgcn_mfma_f32_16x16x32_bf16(pf1, vone8, ol[1], 0, 0, 0);
#pragma unroll
                for (int di = 0; di < 4; di++) {
                    // interleaved V^T: keys {lq*4+i, 16+lq*4+i} contiguous at col lq*8
                    bf16x8 vf = *(const bf16x8*)&lVt[vsw(di * 16 + lr,
                                                         kh * 64 + t2 * 32 + lq * 8)];
                    o[0][di] = __builtin_amdgcn_mfma_f32_16x16x32_bf16(pf0, vf,
                                                                       o[0][di], 0, 0, 0);
                    o[1][di] = __builtin_amdgcn_mfma_f32_16x16x32_bf16(pf1, vf,
                                                                       o[1][di], 0, 0, 0);
                }
                __builtin_amdgcn_s_setprio(0);
            }
        }
    }
    int b = bh >> 4, h = bh & 15;
    if (nsplit == 1) {
#pragma unroll
        for (int tq = 0; tq < 2; tq++) {
#pragma unroll
            for (int di = 0; di < 4; di++)
#pragma unroll
                for (int r = 0; r < 4; r++) {
                    int qg = qb + tq * 16 + lq * 4 + r;
                    part0[((size_t)(b * SEQ + qg)) * D_MODEL + h * 64 + di * 16 + lr] =
                        f2bf(o[tq][di][r] / ol[tq][r]);
                }
        }
    } else {
        u16* pdst = (ks == 0) ? part0 : part1;
#pragma unroll
        for (int tq = 0; tq < 2; tq++)
#pragma unroll
            for (int di = 0; di < 4; di++)
#pragma unroll
                for (int r = 0; r < 4; r++) {
                    int qg = qb + tq * 16 + lq * 4 + r;
                    union { _Float16 h; u16 u; } cv;
                    cv.h = (_Float16)o[tq][di][r];
                    pdst[((size_t)(b * SEQ + qg)) * D_MODEL + h * 64 + di * 16 + lr] =
                        cv.u;
                }
        if (lr == 0) {
#pragma unroll
            for (int tq = 0; tq < 2; tq++)
#pragma unroll
                for (int r = 0; r < 4; r++) {
                    int qg = qb + tq * 16 + lq * 4 + r;
                    lsum[(ks * 32 + bh) * 2048 + qg] = ol[tq][r];
                }
        }
    }
}

extern "C" void kernel_launch(void* const* d_in, const int* in_sizes, int n_in,
                              void* d_out, int out_size, void* d_ws, size_t ws_size,
                              hipStream_t stream) {
    const float* x  = (const float*)d_in[0];
    const float* Wq = (const float*)d_in[1];
    const float* bq = (const float*)d_in[2];
    const float* Wk = (const float*)d_in[3];
    const float* bk = (const float*)d_in[4];
    const float* Wv = (const float*)d_in[5];
    const float* bv = (const float*)d_in[6];
    const float* Wo = (const float*)d_in[7];
    const float* bo = (const float*)d_in[8];
    float* out = (float*)d_out;

    char* ws = (char*)d_ws;
    u16* xb  = (u16*)ws;                               // 0-8 MB: x bf16; later Opart0
    u16* wt  = (u16*)(ws + (size_t)8 * 1024 * 1024);   // 8-16: W^T bf16
    u16* qws = (u16*)(ws + (size_t)16 * 1024 * 1024);  // 16-24: Q (scaled)
    u16* kws = (u16*)(ws + (size_t)24 * 1024 * 1024);  // 24-32: K
    u16* vtw = (u16*)(ws + (size_t)32 * 1024 * 1024);  // 32-40: V^T (key-quad interleaved)
    u16* ao  = (u16*)(ws + (size_t)40 * 1024 * 1024);  // 40-48: attn out / Opart1
    float* ml = (float*)(ws + (size_t)48 * 1024 * 1024); // 48-48.5: split l-sums

    int nsplit = (ws_size >= (size_t)49 * 1024 * 1024) ? 2 : 1;

    k_convert<<<dim3(32, 32, 5), 256, 0, stream>>>(x, Wq, Wk, Wv, Wo, xb, wt);
    k_gemm<<<dim3(8, 32, 3), 256, 0, stream>>>(xb, wt, bq, bk, bv, qws, kws, vtw);
    if (nsplit == 2) {
        k_attn<<<16 * 32 * 2, 256, 0, stream>>>(qws, kws, vtw, xb, ao, ml, 2);
        k_gout<<<dim3(16, 64), 256, 0, stream>>>(xb, ao, ml,
                                                 wt + (size_t)3 * D_MODEL * D_MODEL,
                                                 bo, out);
    } else {
        k_attn<<<16 * 32, 256, 0, stream>>>(qws, kws, vtw, ao, nullptr, ml, 1);
        k_gout<<<dim3(16, 64), 256, 0, stream>>>(ao, nullptr, ml,
                                                 wt + (size_t)3 * D_MODEL * D_MODEL,
                                                 bo, out);
    }
}

// Round 11
// 191.652 us; speedup vs baseline: 1.0556x; 1.0556x over previous
//
#include <hip/hip_runtime.h>

#define D_MODEL 1024
#define NHEAD 16
#define HD 64
#define BATCH 2
#define SEQ 2048

typedef unsigned short u16;
typedef unsigned int u32;
typedef __bf16 bf16x8 __attribute__((ext_vector_type(8)));
typedef unsigned short u16x8 __attribute__((ext_vector_type(8)));
typedef short s16x4 __attribute__((ext_vector_type(4)));
typedef float f32x4 __attribute__((ext_vector_type(4)));

#if defined(__has_builtin)
#if __has_builtin(__builtin_amdgcn_exp2f)
#define EXP2(x) __builtin_amdgcn_exp2f(x)
#else
#define EXP2(x) exp2f(x)
#endif
#else
#define EXP2(x) exp2f(x)
#endif

// fp32 -> bf16 round-to-nearest-even
static __device__ __forceinline__ u16 f2bf(float f) {
    union { float f; unsigned u; } v; v.f = f;
    unsigned u = v.u;
    u += 0x7fffu + ((u >> 16) & 1u);
    return (u16)(u >> 16);
}

static __device__ __forceinline__ void gld_lds16(const void* g, void* l) {
    __builtin_amdgcn_global_load_lds(
        (const __attribute__((address_space(1))) void*)g,
        (__attribute__((address_space(3))) void*)l, 16, 0, 0);
}

// pack 8 fp32 -> 8 bf16 (truncation) via v_perm_b32
static __device__ __forceinline__ bf16x8 pack_bf8(f32x4 a, f32x4 b) {
    union { float f; unsigned u; } a0, a1, a2, a3, b0, b1, b2, b3;
    a0.f = a[0]; a1.f = a[1]; a2.f = a[2]; a3.f = a[3];
    b0.f = b[0]; b1.f = b[1]; b2.f = b[2]; b3.f = b[3];
    union { unsigned u[4]; bf16x8 v; } r;
    r.u[0] = __builtin_amdgcn_perm(a1.u, a0.u, 0x07060302u);
    r.u[1] = __builtin_amdgcn_perm(a3.u, a2.u, 0x07060302u);
    r.u[2] = __builtin_amdgcn_perm(b1.u, b0.u, 0x07060302u);
    r.u[3] = __builtin_amdgcn_perm(b3.u, b2.u, 0x07060302u);
    return r.v;
}

// ---------------- pass 0: x fp32->bf16 (z==0) and W fp32->bf16 transposed (z=1..4) ----------------
__global__ __launch_bounds__(256) void k_convert(const float* __restrict__ x,
                                                 const float* __restrict__ wq,
                                                 const float* __restrict__ wk,
                                                 const float* __restrict__ wv,
                                                 const float* __restrict__ wo,
                                                 u16* __restrict__ xb,
                                                 u16* __restrict__ wt) {
    int z = blockIdx.z;
    if (z == 0) {
        int base = (blockIdx.y * 32 + blockIdx.x) * 256 + threadIdx.x;
#pragma unroll
        for (int p = 0; p < 4; p++) {
            int i = base + p * 262144;
            float4 v = ((const float4*)x)[i];
            ushort4 o = make_ushort4(f2bf(v.x), f2bf(v.y), f2bf(v.z), f2bf(v.w));
            ((ushort4*)xb)[i] = o;
        }
        return;
    }
    __shared__ u16 t[32][33];
    const float* W = z == 1 ? wq : z == 2 ? wk : z == 3 ? wv : wo;
    u16* dst = wt + (size_t)(z - 1) * (D_MODEL * D_MODEL);
    int tx = threadIdx.x & 31, ty = threadIdx.x >> 5;
    int n0 = blockIdx.x * 32, k0 = blockIdx.y * 32;
#pragma unroll
    for (int i = 0; i < 4; i++)
        t[ty + i * 8][tx] = f2bf(W[(size_t)(k0 + ty + i * 8) * D_MODEL + n0 + tx]);
    __syncthreads();
#pragma unroll
    for (int i = 0; i < 4; i++)
        dst[(size_t)(n0 + ty + i * 8) * D_MODEL + k0 + tx] = t[tx][ty + i * 8];
}

// ---------------- QKV GEMM: 128x128 tile, BK=32, double-buffered LDS, T1 swizzle ----------------
// V^T output (z==2) is written with key-quad interleave within each 32-key
// group: k = h*16 + q*4 + i  ->  p = q*8 + h*4 + i. This makes k_attn's PV
// B-frag (keys {lq*4+i} u {16+lq*4+i}) one contiguous b128 at col lq*8.
__global__ __launch_bounds__(256) void k_gemm(const u16* __restrict__ A,
                                              const u16* __restrict__ WtBase,
                                              const float* __restrict__ b0,
                                              const float* __restrict__ b1,
                                              const float* __restrict__ b2,
                                              u16* __restrict__ oq, u16* __restrict__ ok,
                                              u16* __restrict__ ov) {
    __shared__ u16 lA[2 * 128 * 32];   // [buf][row][32]
    __shared__ u16 lB[2 * 128 * 32];
    int tid = threadIdx.x, w = tid >> 6, l = tid & 63, lr = l & 15, lq = l >> 4;
    int z = blockIdx.z;
    const u16* Wt = WtBase + (size_t)z * (D_MODEL * D_MODEL);
    const float* bias = z == 0 ? b0 : z == 1 ? b1 : b2;
    float scale = (z == 0) ? (0.125f * 1.44269504088896340736f) : 1.0f;
    // per-z XCD swizzle: 256 blocks, 256%8==0, q=32
    int fid2 = blockIdx.y * 8 + blockIdx.x;
    int swz = (fid2 & 7) * 32 + (fid2 >> 3);
    int bx = swz & 7, by = swz >> 3;
    int m0 = by * 128, n0 = bx * 128;
    int wm = (w >> 1) * 64, wn = (w & 1) * 64;
    f32x4 acc[4][4];
#pragma unroll
    for (int mi = 0; mi < 4; mi++)
#pragma unroll
        for (int ni = 0; ni < 4; ni++) acc[mi][ni] = (f32x4){0.f, 0.f, 0.f, 0.f};

    int ra = tid >> 2, ca = (tid & 3) * 8;
    const u16* Aba = A + (size_t)(m0 + ra) * D_MODEL + ca;
    const u16* Abb = A + (size_t)(m0 + 64 + ra) * D_MODEL + ca;
    const u16* Bba = Wt + (size_t)(n0 + ra) * D_MODEL + ca;
    const u16* Bbb = Wt + (size_t)(n0 + 64 + ra) * D_MODEL + ca;

    auto stage = [&](int kk, int buf) {
        gld_lds16(Aba + kk, &lA[buf * 4096 + w * 512]);
        gld_lds16(Abb + kk, &lA[buf * 4096 + 2048 + w * 512]);
        gld_lds16(Bba + kk, &lB[buf * 4096 + w * 512]);
        gld_lds16(Bbb + kk, &lB[buf * 4096 + 2048 + w * 512]);
    };

    stage(0, 0);
    __syncthreads();
    int cur = 0;
    for (int t = 0; t < 32; ++t) {
        if (t + 1 < 32) stage((t + 1) * 32, cur ^ 1);
        bf16x8 af[4], bf[4];
#pragma unroll
        for (int mi = 0; mi < 4; mi++)
            af[mi] = *(const bf16x8*)&lA[cur * 4096 + (wm + mi * 16 + lr) * 32 + lq * 8];
#pragma unroll
        for (int ni = 0; ni < 4; ni++)
            bf[ni] = *(const bf16x8*)&lB[cur * 4096 + (wn + ni * 16 + lr) * 32 + lq * 8];
        __builtin_amdgcn_s_setprio(1);
#pragma unroll
        for (int mi = 0; mi < 4; mi++)
#pragma unroll
            for (int ni = 0; ni < 4; ni++)
                acc[mi][ni] = __builtin_amdgcn_mfma_f32_16x16x32_bf16(
                    af[mi], bf[ni], acc[mi][ni], 0, 0, 0);
        __builtin_amdgcn_s_setprio(0);
        __syncthreads();   // vmcnt(0)+lgkmcnt(0)+barrier: publishes buf cur^1
        cur ^= 1;
    }
#pragma unroll
    for (int mi = 0; mi < 4; mi++) {
#pragma unroll
        for (int ni = 0; ni < 4; ni++) {
            int col = n0 + wn + ni * 16 + lr;
            float bval = bias[col];
            int row0 = m0 + wm + mi * 16 + lq * 4;
            if (z == 2) {
                int b = row0 >> 11, s = row0 & 2047;
                int h = col >> 6, dd = col & 63;
                // key-quad interleave: p = (s&~31) | q*8 | h*4  (s%4==0 here)
                int sp = (s & ~31) | ((s & 12) << 1) | ((s & 16) >> 2);
                ushort4 pk;
                pk.x = f2bf(acc[mi][ni][0] + bval);
                pk.y = f2bf(acc[mi][ni][1] + bval);
                pk.z = f2bf(acc[mi][ni][2] + bval);
                pk.w = f2bf(acc[mi][ni][3] + bval);
                *(ushort4*)&ov[((size_t)(b * NHEAD + h) * HD + dd) * SEQ + sp] = pk;
            } else {
#pragma unroll
                for (int r = 0; r < 4; r++) {
                    int row = row0 + r;
                    float val = (acc[mi][ni][r] + bval) * scale;
                    u16* op = z == 0 ? oq : ok;
                    int b = row >> 11, s = row & 2047, h = col >> 6, d = col & 63;
                    op[(((size_t)(b * NHEAD + h)) * SEQ + s) * HD + d] = f2bf(val);
                }
            }
        }
    }
}

// ---------------- output GEMM: 64x64 tiles, BK=64, double-buffered LDS, T1 swizzle ----------------
// BK=64 halves vmcnt(0)+barrier drains (32 -> 16); 8 MFMA + 8 b128 reads +
// 4 gld_lds per drain. Naive [64][64] u16 layout is an 8-way read conflict
// (bank = (c*4)%32, row term vanishes), so staging uses rule #21: linear LDS
// dest + XOR-permuted global SOURCE. Thread l sources col-chunk (l&7)^(l>>3)
// -> chunk c of row R lands at slot c^(R&7); reads apply the same XOR.
// All 8-lane cycle groups hit 8 distinct 4-bank slots: conflict-free.
// LDS 32 KB (unchanged).
__global__ __launch_bounds__(256) void k_gout(const u16* __restrict__ A,
                                              const u16* __restrict__ Wt,
                                              const float* __restrict__ bias,
                                              float* __restrict__ outf) {
    __shared__ u16 lA[2 * 64 * 64];   // [buf][row][64], chunk-swizzled
    __shared__ u16 lB[2 * 64 * 64];
    int tid = threadIdx.x, w = tid >> 6, l = tid & 63, lr = l & 15, lq = l >> 4;
    // 1024 blocks, q=128
    int fid = blockIdx.y * 16 + blockIdx.x;
    int swz = (fid & 7) * 128 + (fid >> 3);
    int bx = swz & 15, by = swz >> 4;
    int m0 = by * 64, n0 = bx * 64;
    int wm = (w >> 1) * 32, wn = (w & 1) * 32;
    f32x4 acc[2][2];
#pragma unroll
    for (int mi = 0; mi < 2; mi++)
#pragma unroll
        for (int ni = 0; ni < 2; ni++) acc[mi][ni] = (f32x4){0.f, 0.f, 0.f, 0.f};

    // staging: call p covers rows 32p + w*8 + (l>>3); source col-chunk (l&7)^(l>>3)
    int srow = w * 8 + (l >> 3);
    int scol = ((l & 7) ^ (l >> 3)) * 8;
    const u16* Aba = A + (size_t)(m0 + srow) * D_MODEL + scol;
    const u16* Bba = Wt + (size_t)(n0 + srow) * D_MODEL + scol;

    auto stage = [&](int kk, int buf) {
        gld_lds16(Aba + kk, &lA[buf * 4096 + w * 512]);
        gld_lds16(Aba + 32 * D_MODEL + kk, &lA[buf * 4096 + 2048 + w * 512]);
        gld_lds16(Bba + kk, &lB[buf * 4096 + w * 512]);
        gld_lds16(Bba + 32 * D_MODEL + kk, &lB[buf * 4096 + 2048 + w * 512]);
    };

    stage(0, 0);
    __syncthreads();
    int cur = 0;
    for (int t = 0; t < 16; ++t) {
        if (t + 1 < 16) stage((t + 1) * 64, cur ^ 1);
        bf16x8 af[2][2], bf[2][2];
#pragma unroll
        for (int kc = 0; kc < 2; kc++) {
#pragma unroll
            for (int mi = 0; mi < 2; mi++) {
                int R = wm + mi * 16 + lr;
                af[kc][mi] = *(const bf16x8*)&lA[cur * 4096 + R * 64 +
                                                 (((kc * 4 + lq) ^ (R & 7)) * 8)];
            }
#pragma unroll
            for (int ni = 0; ni < 2; ni++) {
                int R = wn + ni * 16 + lr;
                bf[kc][ni] = *(const bf16x8*)&lB[cur * 4096 + R * 64 +
                                                 (((kc * 4 + lq) ^ (R & 7)) * 8)];
            }
        }
        __builtin_amdgcn_s_setprio(1);
#pragma unroll
        for (int kc = 0; kc < 2; kc++)
#pragma unroll
            for (int mi = 0; mi < 2; mi++)
#pragma unroll
                for (int ni = 0; ni < 2; ni++)
                    acc[mi][ni] = __builtin_amdgcn_mfma_f32_16x16x32_bf16(
                        af[kc][mi], bf[kc][ni], acc[mi][ni], 0, 0, 0);
        __builtin_amdgcn_s_setprio(0);
        __syncthreads();
        cur ^= 1;
    }
#pragma unroll
    for (int mi = 0; mi < 2; mi++)
#pragma unroll
        for (int ni = 0; ni < 2; ni++) {
            int col = n0 + wn + ni * 16 + lr;
            float bval = bias[col];
#pragma unroll
            for (int r = 0; r < 4; r++) {
                int row = m0 + wm + mi * 16 + lq * 4 + r;
                outf[(size_t)row * D_MODEL + col] = acc[mi][ni][r] + bval;
            }
        }
}

// ---------------- flash attention v11 (R8-proven best: setprio + b128 V-frag) ----------------
static __device__ __forceinline__ int ksw(int row, int col) {  // u16 idx into lK[128][64]
    return row * 64 + ((((col >> 3) ^ (row & 7)) << 3) | (col & 7));
}
static __device__ __forceinline__ int vsw(int row, int col) {  // u16 idx into lVt[64][128]
    return row * 128 + ((((col >> 3) ^ (row & 15)) << 3) | (col & 7));
}

__global__ __launch_bounds__(256) void k_attn(const u16* __restrict__ Q,
                                              const u16* __restrict__ K,
                                              const u16* __restrict__ VT,
                                              u16* __restrict__ part0,
                                              u16* __restrict__ part1,
                                              float* __restrict__ lsum, int nsplit) {
    __shared__ __align__(16) u16 lK[128 * 64];    // XOR-swizzled, see ksw()
    __shared__ __align__(16) u16 lVt[64 * 128];   // XOR-swizzled, see vsw()
    int tid = threadIdx.x, w = tid >> 6, l = tid & 63, lr = l & 15, lq = l >> 4;
    int bl = blockIdx.x;
    int qt = bl / (32 * nsplit);
    int rem = bl - qt * (32 * nsplit);
    int bh = rem / nsplit;
    int ks = rem - bh * nsplit;
    int qb = qt * 128 + w * 32;
    const u16* Qb = Q + (size_t)bh * SEQ * HD;
    const u16* Kb = K + (size_t)bh * SEQ * HD;
    const u16* VTb = VT + (size_t)bh * HD * SEQ;

    bf16x8 qf[2][2];
#pragma unroll
    for (int tq = 0; tq < 2; tq++)
#pragma unroll
        for (int kc = 0; kc < 2; kc++)
            qf[tq][kc] = *(const bf16x8*)&Qb[(size_t)(qb + tq * 16 + lr) * HD +
                                             kc * 32 + lq * 8];
    f32x4 o[2][4];
    f32x4 ol[2];    // l accumulator via ones-MFMA, same C-layout as o
#pragma unroll
    for (int tq = 0; tq < 2; tq++) {
        ol[tq] = (f32x4){0.f, 0.f, 0.f, 0.f};
#pragma unroll
        for (int di = 0; di < 4; di++) o[tq][di] = (f32x4){0.f, 0.f, 0.f, 0.f};
    }
    union { u16 s[8]; bf16x8 v; } onev;
#pragma unroll
    for (int i = 0; i < 8; i++) onev.s[i] = 0x3F80;
    const bf16x8 vone8 = onev.v;

    int krow = tid >> 3, kch = tid & 7;
    int vrow = tid >> 4, vch = tid & 15;

    int nk = SEQ / nsplit;
    int jbeg = ks * nk, jend = jbeg + nk;

    u16x8 kreg[4], vreg[4];
#pragma unroll
    for (int p = 0; p < 4; p++) {
        kreg[p] = *(const u16x8*)&Kb[(size_t)(jbeg + p * 32 + krow) * HD + kch * 8];
        vreg[p] = *(const u16x8*)&VTb[(size_t)(p * 16 + vrow) * SEQ + jbeg + vch * 8];
    }

    for (int j0 = jbeg; j0 < jend; j0 += 128) {
        __syncthreads();
#pragma unroll
        for (int p = 0; p < 4; p++) {
            *(u16x8*)&lK[ksw(p * 32 + krow, kch * 8)] = kreg[p];
            *(u16x8*)&lVt[vsw(p * 16 + vrow, vch * 8)] = vreg[p];
        }
        __syncthreads();
        if (j0 + 128 < jend) {
            int jn = j0 + 128;
#pragma unroll
            for (int p = 0; p < 4; p++) {
                kreg[p] = *(const u16x8*)&Kb[(size_t)(jn + p * 32 + krow) * HD + kch * 8];
                vreg[p] = *(const u16x8*)&VTb[(size_t)(p * 16 + vrow) * SEQ + jn + vch * 8];
            }
        }

#pragma unroll
        for (int kh = 0; kh < 2; kh++) {
#pragma unroll
            for (int t2 = 0; t2 < 2; t2++) {
                int rA = kh * 64 + t2 * 32 + lr;   // key tile A (keys +0..15)
                int rB = rA + 16;                  // key tile B (keys +16..31)
                bf16x8 kA0 = *(const bf16x8*)&lK[ksw(rA, lq * 8)];
                bf16x8 kA1 = *(const bf16x8*)&lK[ksw(rA, 32 + lq * 8)];
                bf16x8 kB0 = *(const bf16x8*)&lK[ksw(rB, lq * 8)];
                bf16x8 kB1 = *(const bf16x8*)&lK[ksw(rB, 32 + lq * 8)];
                f32x4 sA0 = (f32x4){0.f, 0.f, 0.f, 0.f};
                f32x4 sA1 = (f32x4){0.f, 0.f, 0.f, 0.f};
                f32x4 sB0 = (f32x4){0.f, 0.f, 0.f, 0.f};
                f32x4 sB1 = (f32x4){0.f, 0.f, 0.f, 0.f};
                __builtin_amdgcn_s_setprio(1);
                sA0 = __builtin_amdgcn_mfma_f32_16x16x32_bf16(kA0, qf[0][0], sA0, 0, 0, 0);
                sB0 = __builtin_amdgcn_mfma_f32_16x16x32_bf16(kB0, qf[0][0], sB0, 0, 0, 0);
                sA1 = __builtin_amdgcn_mfma_f32_16x16x32_bf16(kA0, qf[1][0], sA1, 0, 0, 0);
                sB1 = __builtin_amdgcn_mfma_f32_16x16x32_bf16(kB0, qf[1][0], sB1, 0, 0, 0);
                sA0 = __builtin_amdgcn_mfma_f32_16x16x32_bf16(kA1, qf[0][1], sA0, 0, 0, 0);
                sB0 = __builtin_amdgcn_mfma_f32_16x16x32_bf16(kB1, qf[0][1], sB0, 0, 0, 0);
                sA1 = __builtin_amdgcn_mfma_f32_16x16x32_bf16(kA1, qf[1][1], sA1, 0, 0, 0);
                sB1 = __builtin_amdgcn_mfma_f32_16x16x32_bf16(kB1, qf[1][1], sB1, 0, 0, 0);
                __builtin_amdgcn_s_setprio(0);
#pragma unroll
                for (int r = 0; r < 4; r++) {
                    sA0[r] = EXP2(sA0[r]);
                    sA1[r] = EXP2(sA1[r]);
                    sB0[r] = EXP2(sB0[r]);
                    sB1[r] = EXP2(sB1[r]);
                }
                bf16x8 pf0 = pack_bf8(sA0, sB0);
                bf16x8 pf1 = pack_bf8(sA1, sB1);
                __builtin_amdgcn_s_setprio(1);
                ol[0] = __builtin_amdgcn_mfma_f32_16x16x32_bf16(pf0, vone8, ol[0], 0, 0, 0);
                ol[1] = __builtin_amdgcn_mfma_f32_16x16x32_bf16(pf1, vone8, ol[1], 0, 0, 0);
#pragma unroll
                for (int di = 0; di < 4; di++) {
                    // interleaved V^T: keys {lq*4+i, 16+lq*4+i} contiguous at col lq*8
                    bf16x8 vf = *(const bf16x8*)&lVt[vsw(di * 16 + lr,
                                                         kh * 64 + t2 * 32 + lq * 8)];
                    o[0][di] = __builtin_amdgcn_mfma_f32_16x16x32_bf16(pf0, vf,
                                                                       o[0][di], 0, 0, 0);
                    o[1][di] = __builtin_amdgcn_mfma_f32_16x16x32_bf16(pf1, vf,
                                                                       o[1][di], 0, 0, 0);
                }
                __builtin_amdgcn_s_setprio(0);
            }
        }
    }
    int b = bh >> 4, h = bh & 15;
    if (nsplit == 1) {
#pragma unroll
        for (int tq = 0; tq < 2; tq++) {
#pragma unroll
            for (int di = 0; di < 4; di++)
#pragma unroll
                for (int r = 0; r < 4; r++) {
                    int qg = qb + tq * 16 + lq * 4 + r;
                    part0[((size_t)(b * SEQ + qg)) * D_MODEL + h * 64 + di * 16 + lr] =
                        f2bf(o[tq][di][r] / ol[tq][r]);
                }
        }
    } else {
        u16* pdst = (ks == 0) ? part0 : part1;
#pragma unroll
        for (int tq = 0; tq < 2; tq++)
#pragma unroll
            for (int di = 0; di < 4; di++)
#pragma unroll
                for (int r = 0; r < 4; r++) {
                    int qg = qb + tq * 16 + lq * 4 + r;
                    union { _Float16 h; u16 u; } cv;
                    cv.h = (_Float16)o[tq][di][r];
                    pdst[((size_t)(b * SEQ + qg)) * D_MODEL + h * 64 + di * 16 + lr] =
                        cv.u;
                }
        if (lr == 0) {
#pragma unroll
            for (int tq = 0; tq < 2; tq++)
#pragma unroll
                for (int r = 0; r < 4; r++) {
                    int qg = qb + tq * 16 + lq * 4 + r;
                    lsum[(ks * 32 + bh) * 2048 + qg] = ol[tq][r];
                }
        }
    }
}

// ---------------- combine 2 key-split partials (shared implicit max) ----------------
__global__ __launch_bounds__(256) void k_combine(const u16* __restrict__ p0,
                                                 const u16* __restrict__ p1,
                                                 const float* __restrict__ lsum,
                                                 u16* __restrict__ dst) {
    int i = blockIdx.x * 256 + threadIdx.x;
    size_t a8 = (size_t)i * 8;
    int row = (int)(a8 >> 10);
    int col = (int)(a8 & 1023);
    int b = row >> 11, q = row & 2047, h = col >> 6;
    int mi = ((b << 4) + h) * 2048 + q;
    float inv = 1.0f / (lsum[mi] + lsum[65536 + mi]);
    u16x8 h0 = *(const u16x8*)(p0 + a8);
    u16x8 h1 = *(const u16x8*)(p1 + a8);
    u16x8 out;
#pragma unroll
    for (int j = 0; j < 8; j++) {
        union { _Float16 h; u16 u; } c0, c1;
        c0.u = h0[j]; c1.u = h1[j];
        out[j] = f2bf(((float)c0.h + (float)c1.h) * inv);
    }
    *(u16x8*)(dst + a8) = out;
}

extern "C" void kernel_launch(void* const* d_in, const int* in_sizes, int n_in,
                              void* d_out, int out_size, void* d_ws, size_t ws_size,
                              hipStream_t stream) {
    const float* x  = (const float*)d_in[0];
    const float* Wq = (const float*)d_in[1];
    const float* bq = (const float*)d_in[2];
    const float* Wk = (const float*)d_in[3];
    const float* bk = (const float*)d_in[4];
    const float* Wv = (const float*)d_in[5];
    const float* bv = (const float*)d_in[6];
    const float* Wo = (const float*)d_in[7];
    const float* bo = (const float*)d_in[8];
    float* out = (float*)d_out;

    char* ws = (char*)d_ws;
    u16* xb  = (u16*)ws;                               // 0-8 MB: x bf16; later Opart0/combined
    u16* wt  = (u16*)(ws + (size_t)8 * 1024 * 1024);   // 8-16: W^T bf16
    u16* qws = (u16*)(ws + (size_t)16 * 1024 * 1024);  // 16-24: Q (scaled)
    u16* kws = (u16*)(ws + (size_t)24 * 1024 * 1024);  // 24-32: K
    u16* vtw = (u16*)(ws + (size_t)32 * 1024 * 1024);  // 32-40: V^T (key-quad interleaved)
    u16* ao  = (u16*)(ws + (size_t)40 * 1024 * 1024);  // 40-48: attn out / Opart1
    float* ml = (float*)(ws + (size_t)48 * 1024 * 1024); // 48-48.5: split l-sums

    int nsplit = (ws_size >= (size_t)49 * 1024 * 1024) ? 2 : 1;
    u16* attn_out = (nsplit == 2) ? xb : ao;   // region gemm2 consumes

    k_convert<<<dim3(32, 32, 5), 256, 0, stream>>>(x, Wq, Wk, Wv, Wo, xb, wt);
    k_gemm<<<dim3(8, 32, 3), 256, 0, stream>>>(xb, wt, bq, bk, bv, qws, kws, vtw);
    if (nsplit == 2) {
        k_attn<<<16 * 32 * 2, 256, 0, stream>>>(qws, kws, vtw, xb, ao, ml, 2);
        k_combine<<<2048, 256, 0, stream>>>(xb, ao, ml, xb);
    } else {
        k_attn<<<16 * 32, 256, 0, stream>>>(qws, kws, vtw, ao, nullptr, ml, 1);
    }
    k_gout<<<dim3(16, 64), 256, 0, stream>>>(attn_out,
                                             wt + (size_t)3 * D_MODEL * D_MODEL,
                                             bo, out);
}

// Round 12
// 185.637 us; speedup vs baseline: 1.0898x; 1.0324x over previous
//
#include <hip/hip_runtime.h>

#define D_MODEL 1024
#define NHEAD 16
#define HD 64
#define BATCH 2
#define SEQ 2048

typedef unsigned short u16;
typedef unsigned int u32;
typedef __bf16 bf16x8 __attribute__((ext_vector_type(8)));
typedef unsigned short u16x8 __attribute__((ext_vector_type(8)));
typedef short s16x4 __attribute__((ext_vector_type(4)));
typedef float f32x4 __attribute__((ext_vector_type(4)));

#if defined(__has_builtin)
#if __has_builtin(__builtin_amdgcn_exp2f)
#define EXP2(x) __builtin_amdgcn_exp2f(x)
#else
#define EXP2(x) exp2f(x)
#endif
#else
#define EXP2(x) exp2f(x)
#endif

// fp32 -> bf16 round-to-nearest-even
static __device__ __forceinline__ u16 f2bf(float f) {
    union { float f; unsigned u; } v; v.f = f;
    unsigned u = v.u;
    u += 0x7fffu + ((u >> 16) & 1u);
    return (u16)(u >> 16);
}

static __device__ __forceinline__ void gld_lds16(const void* g, void* l) {
    __builtin_amdgcn_global_load_lds(
        (const __attribute__((address_space(1))) void*)g,
        (__attribute__((address_space(3))) void*)l, 16, 0, 0);
}

// pack 8 fp32 -> 8 bf16 (truncation) via v_perm_b32
static __device__ __forceinline__ bf16x8 pack_bf8(f32x4 a, f32x4 b) {
    union { float f; unsigned u; } a0, a1, a2, a3, b0, b1, b2, b3;
    a0.f = a[0]; a1.f = a[1]; a2.f = a[2]; a3.f = a[3];
    b0.f = b[0]; b1.f = b[1]; b2.f = b[2]; b3.f = b[3];
    union { unsigned u[4]; bf16x8 v; } r;
    r.u[0] = __builtin_amdgcn_perm(a1.u, a0.u, 0x07060302u);
    r.u[1] = __builtin_amdgcn_perm(a3.u, a2.u, 0x07060302u);
    r.u[2] = __builtin_amdgcn_perm(b1.u, b0.u, 0x07060302u);
    r.u[3] = __builtin_amdgcn_perm(b3.u, b2.u, 0x07060302u);
    return r.v;
}

// ---------------- pass 0: x fp32->bf16 (z==0) and W fp32->bf16 transposed (z=1..4) ----------------
__global__ __launch_bounds__(256) void k_convert(const float* __restrict__ x,
                                                 const float* __restrict__ wq,
                                                 const float* __restrict__ wk,
                                                 const float* __restrict__ wv,
                                                 const float* __restrict__ wo,
                                                 u16* __restrict__ xb,
                                                 u16* __restrict__ wt) {
    int z = blockIdx.z;
    if (z == 0) {
        int base = (blockIdx.y * 32 + blockIdx.x) * 256 + threadIdx.x;
#pragma unroll
        for (int p = 0; p < 4; p++) {
            int i = base + p * 262144;
            float4 v = ((const float4*)x)[i];
            ushort4 o = make_ushort4(f2bf(v.x), f2bf(v.y), f2bf(v.z), f2bf(v.w));
            ((ushort4*)xb)[i] = o;
        }
        return;
    }
    __shared__ u16 t[32][33];
    const float* W = z == 1 ? wq : z == 2 ? wk : z == 3 ? wv : wo;
    u16* dst = wt + (size_t)(z - 1) * (D_MODEL * D_MODEL);
    int tx = threadIdx.x & 31, ty = threadIdx.x >> 5;
    int n0 = blockIdx.x * 32, k0 = blockIdx.y * 32;
#pragma unroll
    for (int i = 0; i < 4; i++)
        t[ty + i * 8][tx] = f2bf(W[(size_t)(k0 + ty + i * 8) * D_MODEL + n0 + tx]);
    __syncthreads();
#pragma unroll
    for (int i = 0; i < 4; i++)
        dst[(size_t)(n0 + ty + i * 8) * D_MODEL + k0 + tx] = t[tx][ty + i * 8];
}

// ---------------- QKV GEMM: 128x128 tile, BK=32, double-buffered LDS, T1 swizzle ----------------
// V^T output (z==2) is written with key-quad interleave within each 32-key
// group: k = h*16 + q*4 + i  ->  p = q*8 + h*4 + i. This makes k_attn's PV
// B-frag (keys {lq*4+i} u {16+lq*4+i}) one contiguous b128 at col lq*8.
__global__ __launch_bounds__(256) void k_gemm(const u16* __restrict__ A,
                                              const u16* __restrict__ WtBase,
                                              const float* __restrict__ b0,
                                              const float* __restrict__ b1,
                                              const float* __restrict__ b2,
                                              u16* __restrict__ oq, u16* __restrict__ ok,
                                              u16* __restrict__ ov) {
    __shared__ u16 lA[2 * 128 * 32];   // [buf][row][32]
    __shared__ u16 lB[2 * 128 * 32];
    int tid = threadIdx.x, w = tid >> 6, l = tid & 63, lr = l & 15, lq = l >> 4;
    int z = blockIdx.z;
    const u16* Wt = WtBase + (size_t)z * (D_MODEL * D_MODEL);
    const float* bias = z == 0 ? b0 : z == 1 ? b1 : b2;
    float scale = (z == 0) ? (0.125f * 1.44269504088896340736f) : 1.0f;
    // per-z XCD swizzle: 256 blocks, 256%8==0, q=32
    int fid2 = blockIdx.y * 8 + blockIdx.x;
    int swz = (fid2 & 7) * 32 + (fid2 >> 3);
    int bx = swz & 7, by = swz >> 3;
    int m0 = by * 128, n0 = bx * 128;
    int wm = (w >> 1) * 64, wn = (w & 1) * 64;
    f32x4 acc[4][4];
#pragma unroll
    for (int mi = 0; mi < 4; mi++)
#pragma unroll
        for (int ni = 0; ni < 4; ni++) acc[mi][ni] = (f32x4){0.f, 0.f, 0.f, 0.f};

    int ra = tid >> 2, ca = (tid & 3) * 8;
    const u16* Aba = A + (size_t)(m0 + ra) * D_MODEL + ca;
    const u16* Abb = A + (size_t)(m0 + 64 + ra) * D_MODEL + ca;
    const u16* Bba = Wt + (size_t)(n0 + ra) * D_MODEL + ca;
    const u16* Bbb = Wt + (size_t)(n0 + 64 + ra) * D_MODEL + ca;

    auto stage = [&](int kk, int buf) {
        gld_lds16(Aba + kk, &lA[buf * 4096 + w * 512]);
        gld_lds16(Abb + kk, &lA[buf * 4096 + 2048 + w * 512]);
        gld_lds16(Bba + kk, &lB[buf * 4096 + w * 512]);
        gld_lds16(Bbb + kk, &lB[buf * 4096 + 2048 + w * 512]);
    };

    stage(0, 0);
    __syncthreads();
    int cur = 0;
    for (int t = 0; t < 32; ++t) {
        if (t + 1 < 32) stage((t + 1) * 32, cur ^ 1);
        bf16x8 af[4], bf[4];
#pragma unroll
        for (int mi = 0; mi < 4; mi++)
            af[mi] = *(const bf16x8*)&lA[cur * 4096 + (wm + mi * 16 + lr) * 32 + lq * 8];
#pragma unroll
        for (int ni = 0; ni < 4; ni++)
            bf[ni] = *(const bf16x8*)&lB[cur * 4096 + (wn + ni * 16 + lr) * 32 + lq * 8];
        __builtin_amdgcn_s_setprio(1);
#pragma unroll
        for (int mi = 0; mi < 4; mi++)
#pragma unroll
            for (int ni = 0; ni < 4; ni++)
                acc[mi][ni] = __builtin_amdgcn_mfma_f32_16x16x32_bf16(
                    af[mi], bf[ni], acc[mi][ni], 0, 0, 0);
        __builtin_amdgcn_s_setprio(0);
        __syncthreads();   // vmcnt(0)+lgkmcnt(0)+barrier: publishes buf cur^1
        cur ^= 1;
    }
#pragma unroll
    for (int mi = 0; mi < 4; mi++) {
#pragma unroll
        for (int ni = 0; ni < 4; ni++) {
            int col = n0 + wn + ni * 16 + lr;
            float bval = bias[col];
            int row0 = m0 + wm + mi * 16 + lq * 4;
            if (z == 2) {
                int b = row0 >> 11, s = row0 & 2047;
                int h = col >> 6, dd = col & 63;
                // key-quad interleave: p = (s&~31) | q*8 | h*4  (s%4==0 here)
                int sp = (s & ~31) | ((s & 12) << 1) | ((s & 16) >> 2);
                ushort4 pk;
                pk.x = f2bf(acc[mi][ni][0] + bval);
                pk.y = f2bf(acc[mi][ni][1] + bval);
                pk.z = f2bf(acc[mi][ni][2] + bval);
                pk.w = f2bf(acc[mi][ni][3] + bval);
                *(ushort4*)&ov[((size_t)(b * NHEAD + h) * HD + dd) * SEQ + sp] = pk;
            } else {
#pragma unroll
                for (int r = 0; r < 4; r++) {
                    int row = row0 + r;
                    float val = (acc[mi][ni][r] + bval) * scale;
                    u16* op = z == 0 ? oq : ok;
                    int b = row >> 11, s = row & 2047, h = col >> 6, d = col & 63;
                    op[(((size_t)(b * NHEAD + h)) * SEQ + s) * HD + d] = f2bf(val);
                }
            }
        }
    }
}

// ---------------- output GEMM: 64x64 tiles, BK=32, double-buffered LDS, T1 swizzle ----------------
__global__ __launch_bounds__(256) void k_gout(const u16* __restrict__ A,
                                              const u16* __restrict__ Wt,
                                              const float* __restrict__ bias,
                                              float* __restrict__ outf) {
    __shared__ u16 lA[2 * 64 * 32];
    __shared__ u16 lB[2 * 64 * 32];
    int tid = threadIdx.x, w = tid >> 6, l = tid & 63, lr = l & 15, lq = l >> 4;
    // 1024 blocks, q=128
    int fid = blockIdx.y * 16 + blockIdx.x;
    int swz = (fid & 7) * 128 + (fid >> 3);
    int bx = swz & 15, by = swz >> 4;
    int m0 = by * 64, n0 = bx * 64;
    int wm = (w >> 1) * 32, wn = (w & 1) * 32;
    f32x4 acc[2][2];
#pragma unroll
    for (int mi = 0; mi < 2; mi++)
#pragma unroll
        for (int ni = 0; ni < 2; ni++) acc[mi][ni] = (f32x4){0.f, 0.f, 0.f, 0.f};

    int ra = tid >> 2, ca = (tid & 3) * 8;
    const u16* Aba = A + (size_t)(m0 + ra) * D_MODEL + ca;
    const u16* Bba = Wt + (size_t)(n0 + ra) * D_MODEL + ca;

    auto stage = [&](int kk, int buf) {
        gld_lds16(Aba + kk, &lA[buf * 2048 + w * 512]);
        gld_lds16(Bba + kk, &lB[buf * 2048 + w * 512]);
    };

    stage(0, 0);
    __syncthreads();
    int cur = 0;
    for (int t = 0; t < 32; ++t) {
        if (t + 1 < 32) stage((t + 1) * 32, cur ^ 1);
        bf16x8 af[2], bf[2];
#pragma unroll
        for (int mi = 0; mi < 2; mi++)
            af[mi] = *(const bf16x8*)&lA[cur * 2048 + (wm + mi * 16 + lr) * 32 + lq * 8];
#pragma unroll
        for (int ni = 0; ni < 2; ni++)
            bf[ni] = *(const bf16x8*)&lB[cur * 2048 + (wn + ni * 16 + lr) * 32 + lq * 8];
        __builtin_amdgcn_s_setprio(1);
#pragma unroll
        for (int mi = 0; mi < 2; mi++)
#pragma unroll
            for (int ni = 0; ni < 2; ni++)
                acc[mi][ni] = __builtin_amdgcn_mfma_f32_16x16x32_bf16(
                    af[mi], bf[ni], acc[mi][ni], 0, 0, 0);
        __builtin_amdgcn_s_setprio(0);
        __syncthreads();
        cur ^= 1;
    }
#pragma unroll
    for (int mi = 0; mi < 2; mi++)
#pragma unroll
        for (int ni = 0; ni < 2; ni++) {
            int col = n0 + wn + ni * 16 + lr;
            float bval = bias[col];
#pragma unroll
            for (int r = 0; r < 4; r++) {
                int row = m0 + wm + mi * 16 + lq * 4 + r;
                outf[(size_t)row * D_MODEL + col] = acc[mi][ni][r] + bval;
            }
        }
}

// ---------------- flash attention v13: v11 + wave-staggered units + exp/PV interleave ----------------
// The block's 4 waves leave each barrier together and march through identical
// code -> all do QK at once (trans idle), all exp at once (matrix idle).
// Wave w processes units in order (uu+w)&3 (legal: units are independent up
// to fp-accumulation order), decorrelating the phases so one wave's exp
// overlaps another's MFMAs on the same SIMD. Also: exp of the second score
// half is placed AFTER the first half's PV issue, shortening each unit's
// serial chain. u feeds only address arithmetic (rule #20 safe).
static __device__ __forceinline__ int ksw(int row, int col) {  // u16 idx into lK[128][64]
    return row * 64 + ((((col >> 3) ^ (row & 7)) << 3) | (col & 7));
}
static __device__ __forceinline__ int vsw(int row, int col) {  // u16 idx into lVt[64][128]
    return row * 128 + ((((col >> 3) ^ (row & 15)) << 3) | (col & 7));
}

__global__ __launch_bounds__(256) void k_attn(const u16* __restrict__ Q,
                                              const u16* __restrict__ K,
                                              const u16* __restrict__ VT,
                                              u16* __restrict__ part0,
                                              u16* __restrict__ part1,
                                              float* __restrict__ lsum, int nsplit) {
    __shared__ __align__(16) u16 lK[128 * 64];    // XOR-swizzled, see ksw()
    __shared__ __align__(16) u16 lVt[64 * 128];   // XOR-swizzled, see vsw()
    int tid = threadIdx.x, w = tid >> 6, l = tid & 63, lr = l & 15, lq = l >> 4;
    int bl = blockIdx.x;
    int qt = bl / (32 * nsplit);
    int rem = bl - qt * (32 * nsplit);
    int bh = rem / nsplit;
    int ks = rem - bh * nsplit;
    int qb = qt * 128 + w * 32;
    const u16* Qb = Q + (size_t)bh * SEQ * HD;
    const u16* Kb = K + (size_t)bh * SEQ * HD;
    const u16* VTb = VT + (size_t)bh * HD * SEQ;

    bf16x8 qf[2][2];
#pragma unroll
    for (int tq = 0; tq < 2; tq++)
#pragma unroll
        for (int kc = 0; kc < 2; kc++)
            qf[tq][kc] = *(const bf16x8*)&Qb[(size_t)(qb + tq * 16 + lr) * HD +
                                             kc * 32 + lq * 8];
    f32x4 o[2][4];
    f32x4 ol[2];    // l accumulator via ones-MFMA, same C-layout as o
#pragma unroll
    for (int tq = 0; tq < 2; tq++) {
        ol[tq] = (f32x4){0.f, 0.f, 0.f, 0.f};
#pragma unroll
        for (int di = 0; di < 4; di++) o[tq][di] = (f32x4){0.f, 0.f, 0.f, 0.f};
    }
    union { u16 s[8]; bf16x8 v; } onev;
#pragma unroll
    for (int i = 0; i < 8; i++) onev.s[i] = 0x3F80;
    const bf16x8 vone8 = onev.v;

    int krow = tid >> 3, kch = tid & 7;
    int vrow = tid >> 4, vch = tid & 15;

    int nk = SEQ / nsplit;
    int jbeg = ks * nk, jend = jbeg + nk;

    u16x8 kreg[4], vreg[4];
#pragma unroll
    for (int p = 0; p < 4; p++) {
        kreg[p] = *(const u16x8*)&Kb[(size_t)(jbeg + p * 32 + krow) * HD + kch * 8];
        vreg[p] = *(const u16x8*)&VTb[(size_t)(p * 16 + vrow) * SEQ + jbeg + vch * 8];
    }

    for (int j0 = jbeg; j0 < jend; j0 += 128) {
        __syncthreads();
#pragma unroll
        for (int p = 0; p < 4; p++) {
            *(u16x8*)&lK[ksw(p * 32 + krow, kch * 8)] = kreg[p];
            *(u16x8*)&lVt[vsw(p * 16 + vrow, vch * 8)] = vreg[p];
        }
        __syncthreads();
        if (j0 + 128 < jend) {
            int jn = j0 + 128;
#pragma unroll
            for (int p = 0; p < 4; p++) {
                kreg[p] = *(const u16x8*)&Kb[(size_t)(jn + p * 32 + krow) * HD + kch * 8];
                vreg[p] = *(const u16x8*)&VTb[(size_t)(p * 16 + vrow) * SEQ + jn + vch * 8];
            }
        }

#pragma unroll
        for (int uu = 0; uu < 4; uu++) {
            int u = (uu + w) & 3;              // wave-staggered unit order
            int rA = u * 32 + lr;              // key tile A (keys +0..15)
            int rB = rA + 16;                  // key tile B (keys +16..31)
            bf16x8 kA0 = *(const bf16x8*)&lK[ksw(rA, lq * 8)];
            bf16x8 kA1 = *(const bf16x8*)&lK[ksw(rA, 32 + lq * 8)];
            bf16x8 kB0 = *(const bf16x8*)&lK[ksw(rB, lq * 8)];
            bf16x8 kB1 = *(const bf16x8*)&lK[ksw(rB, 32 + lq * 8)];
            f32x4 sA0 = (f32x4){0.f, 0.f, 0.f, 0.f};
            f32x4 sA1 = (f32x4){0.f, 0.f, 0.f, 0.f};
            f32x4 sB0 = (f32x4){0.f, 0.f, 0.f, 0.f};
            f32x4 sB1 = (f32x4){0.f, 0.f, 0.f, 0.f};
            __builtin_amdgcn_s_setprio(1);
            sA0 = __builtin_amdgcn_mfma_f32_16x16x32_bf16(kA0, qf[0][0], sA0, 0, 0, 0);
            sB0 = __builtin_amdgcn_mfma_f32_16x16x32_bf16(kB0, qf[0][0], sB0, 0, 0, 0);
            sA1 = __builtin_amdgcn_mfma_f32_16x16x32_bf16(kA0, qf[1][0], sA1, 0, 0, 0);
            sB1 = __builtin_amdgcn_mfma_f32_16x16x32_bf16(kB0, qf[1][0], sB1, 0, 0, 0);
            sA0 = __builtin_amdgcn_mfma_f32_16x16x32_bf16(kA1, qf[0][1], sA0, 0, 0, 0);
            sB0 = __builtin_amdgcn_mfma_f32_16x16x32_bf16(kB1, qf[0][1], sB0, 0, 0, 0);
            sA1 = __builtin_amdgcn_mfma_f32_16x16x32_bf16(kA1, qf[1][1], sA1, 0, 0, 0);
            sB1 = __builtin_amdgcn_mfma_f32_16x16x32_bf16(kB1, qf[1][1], sB1, 0, 0, 0);
            __builtin_amdgcn_s_setprio(0);
            // V frags (independent of scores; interleaved V^T: keys
            // {lq*4+i, 16+lq*4+i} contiguous at col u*32 + lq*8)
            bf16x8 vf0 = *(const bf16x8*)&lVt[vsw(0 * 16 + lr, u * 32 + lq * 8)];
            bf16x8 vf1 = *(const bf16x8*)&lVt[vsw(1 * 16 + lr, u * 32 + lq * 8)];
            bf16x8 vf2 = *(const bf16x8*)&lVt[vsw(2 * 16 + lr, u * 32 + lq * 8)];
            bf16x8 vf3 = *(const bf16x8*)&lVt[vsw(3 * 16 + lr, u * 32 + lq * 8)];
            // first half: exp + pack + PV issue (tq=0)
#pragma unroll
            for (int r = 0; r < 4; r++) {
                sA0[r] = EXP2(sA0[r]);
                sB0[r] = EXP2(sB0[r]);
            }
            bf16x8 pf0 = pack_bf8(sA0, sB0);
            __builtin_amdgcn_s_setprio(1);
            ol[0] = __builtin_amdgcn_mfma_f32_16x16x32_bf16(pf0, vone8, ol[0], 0, 0, 0);
            o[0][0] = __builtin_amdgcn_mfma_f32_16x16x32_bf16(pf0, vf0, o[0][0], 0, 0, 0);
            o[0][1] = __builtin_amdgcn_mfma_f32_16x16x32_bf16(pf0, vf1, o[0][1], 0, 0, 0);
            o[0][2] = __builtin_amdgcn_mfma_f32_16x16x32_bf16(pf0, vf2, o[0][2], 0, 0, 0);
            o[0][3] = __builtin_amdgcn_mfma_f32_16x16x32_bf16(pf0, vf3, o[0][3], 0, 0, 0);
            __builtin_amdgcn_s_setprio(0);
            // second half: exp overlaps first half's PV in the matrix pipe
#pragma unroll
            for (int r = 0; r < 4; r++) {
                sA1[r] = EXP2(sA1[r]);
                sB1[r] = EXP2(sB1[r]);
            }
            bf16x8 pf1 = pack_bf8(sA1, sB1);
            __builtin_amdgcn_s_setprio(1);
            ol[1] = __builtin_amdgcn_mfma_f32_16x16x32_bf16(pf1, vone8, ol[1], 0, 0, 0);
            o[1][0] = __builtin_amdgcn_mfma_f32_16x16x32_bf16(pf1, vf0, o[1][0], 0, 0, 0);
            o[1][1] = __builtin_amdgcn_mfma_f32_16x16x32_bf16(pf1, vf1, o[1][1], 0, 0, 0);
            o[1][2] = __builtin_amdgcn_mfma_f32_16x16x32_bf16(pf1, vf2, o[1][2], 0, 0, 0);
            o[1][3] = __builtin_amdgcn_mfma_f32_16x16x32_bf16(pf1, vf3, o[1][3], 0, 0, 0);
            __builtin_amdgcn_s_setprio(0);
        }
    }
    int b = bh >> 4, h = bh & 15;
    if (nsplit == 1) {
#pragma unroll
        for (int tq = 0; tq < 2; tq++) {
#pragma unroll
            for (int di = 0; di < 4; di++)
#pragma unroll
                for (int r = 0; r < 4; r++) {
                    int qg = qb + tq * 16 + lq * 4 + r;
                    part0[((size_t)(b * SEQ + qg)) * D_MODEL + h * 64 + di * 16 + lr] =
                        f2bf(o[tq][di][r] / ol[tq][r]);
                }
        }
    } else {
        u16* pdst = (ks == 0) ? part0 : part1;
#pragma unroll
        for (int tq = 0; tq < 2; tq++)
#pragma unroll
            for (int di = 0; di < 4; di++)
#pragma unroll
                for (int r = 0; r < 4; r++) {
                    int qg = qb + tq * 16 + lq * 4 + r;
                    union { _Float16 h; u16 u; } cv;
                    cv.h = (_Float16)o[tq][di][r];
                    pdst[((size_t)(b * SEQ + qg)) * D_MODEL + h * 64 + di * 16 + lr] =
                        cv.u;
                }
        if (lr == 0) {
#pragma unroll
            for (int tq = 0; tq < 2; tq++)
#pragma unroll
                for (int r = 0; r < 4; r++) {
                    int qg = qb + tq * 16 + lq * 4 + r;
                    lsum[(ks * 32 + bh) * 2048 + qg] = ol[tq][r];
                }
        }
    }
}

// ---------------- combine 2 key-split partials (shared implicit max) ----------------
__global__ __launch_bounds__(256) void k_combine(const u16* __restrict__ p0,
                                                 const u16* __restrict__ p1,
                                                 const float* __restrict__ lsum,
                                                 u16* __restrict__ dst) {
    int i = blockIdx.x * 256 + threadIdx.x;
    size_t a8 = (size_t)i * 8;
    int row = (int)(a8 >> 10);
    int col = (int)(a8 & 1023);
    int b = row >> 11, q = row & 2047, h = col >> 6;
    int mi = ((b << 4) + h) * 2048 + q;
    float inv = 1.0f / (lsum[mi] + lsum[65536 + mi]);
    u16x8 h0 = *(const u16x8*)(p0 + a8);
    u16x8 h1 = *(const u16x8*)(p1 + a8);
    u16x8 out;
#pragma unroll
    for (int j = 0; j < 8; j++) {
        union { _Float16 h; u16 u; } c0, c1;
        c0.u = h0[j]; c1.u = h1[j];
        out[j] = f2bf(((float)c0.h + (float)c1.h) * inv);
    }
    *(u16x8*)(dst + a8) = out;
}

extern "C" void kernel_launch(void* const* d_in, const int* in_sizes, int n_in,
                              void* d_out, int out_size, void* d_ws, size_t ws_size,
                              hipStream_t stream) {
    const float* x  = (const float*)d_in[0];
    const float* Wq = (const float*)d_in[1];
    const float* bq = (const float*)d_in[2];
    const float* Wk = (const float*)d_in[3];
    const float* bk = (const float*)d_in[4];
    const float* Wv = (const float*)d_in[5];
    const float* bv = (const float*)d_in[6];
    const float* Wo = (const float*)d_in[7];
    const float* bo = (const float*)d_in[8];
    float* out = (float*)d_out;

    char* ws = (char*)d_ws;
    u16* xb  = (u16*)ws;                               // 0-8 MB: x bf16; later Opart0/combined
    u16* wt  = (u16*)(ws + (size_t)8 * 1024 * 1024);   // 8-16: W^T bf16
    u16* qws = (u16*)(ws + (size_t)16 * 1024 * 1024);  // 16-24: Q (scaled)
    u16* kws = (u16*)(ws + (size_t)24 * 1024 * 1024);  // 24-32: K
    u16* vtw = (u16*)(ws + (size_t)32 * 1024 * 1024);  // 32-40: V^T (key-quad interleaved)
    u16* ao  = (u16*)(ws + (size_t)40 * 1024 * 1024);  // 40-48: attn out / Opart1
    float* ml = (float*)(ws + (size_t)48 * 1024 * 1024); // 48-48.5: split l-sums

    int nsplit = (ws_size >= (size_t)49 * 1024 * 1024) ? 2 : 1;
    u16* attn_out = (nsplit == 2) ? xb : ao;   // region gemm2 consumes

    k_convert<<<dim3(32, 32, 5), 256, 0, stream>>>(x, Wq, Wk, Wv, Wo, xb, wt);
    k_gemm<<<dim3(8, 32, 3), 256, 0, stream>>>(xb, wt, bq, bk, bv, qws, kws, vtw);
    if (nsplit == 2) {
        k_attn<<<16 * 32 * 2, 256, 0, stream>>>(qws, kws, vtw, xb, ao, ml, 2);
        k_combine<<<2048, 256, 0, stream>>>(xb, ao, ml, xb);
    } else {
        k_attn<<<16 * 32, 256, 0, stream>>>(qws, kws, vtw, ao, nullptr, ml, 1);
    }
    k_gout<<<dim3(16, 64), 256, 0, stream>>>(attn_out,
                                             wt + (size_t)3 * D_MODEL * D_MODEL,
                                             bo, out);
}